// Round 13
// baseline (66.127 us; speedup 1.0000x reference)
//
#include <hip/hip_runtime.h>

// Problem constants (match reference.py)
#define NB 65536   // trajectories
#define NT 512     // time points (NT-1 steps)

typedef float f32x2 __attribute__((ext_vector_type(2)));
typedef float f32x4 __attribute__((ext_vector_type(4)));

// R13 = R9 structure + R11 spine algebra, ISOLATED from R11's bad layout.
// Identical to R9 (62.5us best): one ds_read_b128/step of {h2,h6,D,dt},
// plain cached stores, unroll 8, 1 traj/thread (1 wave/SIMD).
// Changed (algebra only, all operands from registers):
//   h2D = h2*D, dtD = dt*D formed per step (off-chain muls)
//   den_{i+1} = fma(-h, rb_i, brk_{i+1}),  brk_{i+1} = fma(hD, ses_i, sK)
//     -> rb->den is ONE dependent fma (was two); brk arrives early via the
//        short path rb1->k1s->ss_i->ses_i (~20cy) vs spine rcp (~32cy)
//   carried sK: sK' = fma(h6, sst, sK) -> next rcp starts from sst directly
__global__ __launch_bounds__(256) void rk4_biosystem_kernel(
    const float* __restrict__ y0,
    const float* __restrict__ t_eval,
    const float* __restrict__ D_seq,
    const float* __restrict__ K_m_p,
    const float* __restrict__ s_e_p,
    const float* __restrict__ mu_max_p,
    float* __restrict__ out)
{
    __shared__ f32x4 u4[NT];   // {h2, h6, D, dt} per step; 8 KiB

    const int tid = threadIdx.x;
    for (int i = tid; i < NT; i += 256) {
        const int j = (i < NT - 1) ? i : (NT - 2);   // pad tail (never used)
        const float dt = t_eval[j + 1] - t_eval[j];  // dt exactly as reference
        f32x4 v;
        v.x = dt * 0.5f;
        v.y = dt * (1.0f / 6.0f);
        v.z = D_seq[j];
        v.w = dt;
        u4[i] = v;
    }
    __syncthreads();

    const float K_m    = K_m_p[0];
    const float s_e    = s_e_p[0];
    const float mu_max = mu_max_p[0];

    const int traj = blockIdx.x * 256 + tid;

    const f32x2* __restrict__ y0v = (const f32x2*)y0;
    f32x2 y = y0v[traj];                    // (b, s)
    float b = y.x, s = y.y;

    f32x2* __restrict__ out2 = (f32x2*)out; // out[t][traj][2] as vec2
    out2[traj] = y;                         // row 0 = y0
    f32x2* __restrict__ op = out2 + traj;   // walking output pointer

    float sK = K_m + s;                     // carried: K_m + s (spine head)

    #pragma unroll 8
    for (int t = 0; t < NT - 1; ++t) {
        const f32x4 u = u4[t];
        const float h2 = u.x, h6 = u.y, D = u.z, dt = u.w;
        const float h2D = h2 * D;           // off-chain
        const float dtD = dt * D;           // off-chain

        const float ses = s_e - s;          // off-chain
        const float ms  = mu_max * s;

        // ---- stage 1 ----
        const float inv1 = __builtin_amdgcn_rcpf(sK);
        const float num1 = ms * b;
        const float rb1  = num1 * inv1;
        const float brk2 = __builtin_fmaf(h2D, ses, sK);    // early
        const float den2 = __builtin_fmaf(-h2, rb1, brk2);  // rb1->den2: 1 fma
        const float k1b  = __builtin_fmaf(-D, b, rb1);
        const float k1s  = __builtin_fmaf(D, ses, -rb1);

        // ---- stage 2 ----
        const float inv2 = __builtin_amdgcn_rcpf(den2);
        const float bb2  = __builtin_fmaf(h2, k1b, b);
        const float ss2  = __builtin_fmaf(h2, k1s, s);
        const float ses2 = s_e - ss2;
        const float num2 = (mu_max * ss2) * bb2;
        const float rb2  = num2 * inv2;
        const float brk3 = __builtin_fmaf(h2D, ses2, sK);
        const float den3 = __builtin_fmaf(-h2, rb2, brk3);
        const float k2b  = __builtin_fmaf(-D, bb2, rb2);
        const float k2s  = __builtin_fmaf(D, ses2, -rb2);

        // ---- stage 3 ----
        const float inv3 = __builtin_amdgcn_rcpf(den3);
        const float bb3  = __builtin_fmaf(h2, k2b, b);
        const float ss3  = __builtin_fmaf(h2, k2s, s);
        const float ses3 = s_e - ss3;
        const float num3 = (mu_max * ss3) * bb3;
        const float rb3  = num3 * inv3;
        const float brk4 = __builtin_fmaf(dtD, ses3, sK);
        const float den4 = __builtin_fmaf(-dt, rb3, brk4);
        const float k3b  = __builtin_fmaf(-D, bb3, rb3);
        const float k3s  = __builtin_fmaf(D, ses3, -rb3);

        // ---- stage 4 ----
        const float inv4 = __builtin_amdgcn_rcpf(den4);
        const float bb4  = __builtin_fmaf(dt, k3b, b);
        const float ss4  = __builtin_fmaf(dt, k3s, s);
        const float ses4 = s_e - ss4;
        const float num4 = (mu_max * ss4) * bb4;
        const float rb4  = num4 * inv4;
        const float k4b  = __builtin_fmaf(-D, bb4, rb4);
        const float k4s  = __builtin_fmaf(D, ses4, -rb4);

        // ---- k-sums + update; sK first (next spine head) ----
        const float sbt = (k1b + k4b) + 2.0f * (k2b + k3b);
        const float sst = (k1s + k4s) + 2.0f * (k2s + k3s);
        sK = __builtin_fmaf(h6, sst, sK);
        b  = __builtin_fmaf(h6, sbt, b);
        s  = __builtin_fmaf(h6, sst, s);

        op += NB;
        f32x2 v; v.x = b; v.y = s;
        *op = v;
    }
}

extern "C" void kernel_launch(void* const* d_in, const int* in_sizes, int n_in,
                              void* d_out, int out_size, void* d_ws, size_t ws_size,
                              hipStream_t stream) {
    const float* y0     = (const float*)d_in[0];
    const float* t_eval = (const float*)d_in[1];
    const float* D_seq  = (const float*)d_in[2];
    const float* K_m    = (const float*)d_in[3];
    const float* s_e    = (const float*)d_in[4];
    const float* mu_max = (const float*)d_in[5];
    float* out = (float*)d_out;

    dim3 grid(NB / 256);
    dim3 block(256);
    rk4_biosystem_kernel<<<grid, block, 0, stream>>>(y0, t_eval, D_seq, K_m, s_e, mu_max, out);
}

// Round 14
// 60.809 us; speedup vs baseline: 1.0875x; 1.0875x over previous
//
#include <hip/hip_runtime.h>

// Problem constants (match reference.py)
#define NB 65536   // trajectories
#define NT 512     // time points (NT-1 steps)

typedef float f32x2 __attribute__((ext_vector_type(2)));
typedef float f32x4 __attribute__((ext_vector_type(4)));

// R14 = R9 body (62.5us best, 294 cyc/step) with two scheduling knobs:
//   - unroll 16 (wider ds_read batch + store-reg rotation window)
//   - __launch_bounds__(256, 1): occupancy is structurally 1 wave/EU
//     (65536 threads = 1024 waves on 1024 SIMDs), so give the register
//     allocator the full budget.
// Ledger (measured): TLP trades lose (R4 -68%, R7 -49%); vmcnt-path uniforms
// lose (R8 -48%); any instruction-footprint growth loses ~3.4 cyc/inst
// (R10/R11/R13); issue trims beyond R9 are null. Floor: max(chain ~40us,
// write drain ~39us).
__global__ __launch_bounds__(256, 1) void rk4_biosystem_kernel(
    const float* __restrict__ y0,
    const float* __restrict__ t_eval,
    const float* __restrict__ D_seq,
    const float* __restrict__ K_m_p,
    const float* __restrict__ s_e_p,
    const float* __restrict__ mu_max_p,
    float* __restrict__ out)
{
    __shared__ f32x4 u4[NT];   // {h2, h6, D, dt} per step; 8 KiB

    const int tid = threadIdx.x;
    for (int i = tid; i < NT; i += 256) {
        const int j = (i < NT - 1) ? i : (NT - 2);   // pad tail (never used)
        const float dt = t_eval[j + 1] - t_eval[j];  // dt exactly as reference
        f32x4 v;
        v.x = dt * 0.5f;
        v.y = dt * (1.0f / 6.0f);
        v.z = D_seq[j];
        v.w = dt;
        u4[i] = v;
    }
    __syncthreads();

    const float K_m    = K_m_p[0];
    const float s_e    = s_e_p[0];
    const float mu_max = mu_max_p[0];

    const int traj = blockIdx.x * 256 + tid;

    const f32x2* __restrict__ y0v = (const f32x2*)y0;
    f32x2 y = y0v[traj];                    // (b, s)
    float b = y.x, s = y.y;

    f32x2* __restrict__ out2 = (f32x2*)out; // out[t][traj][2] as vec2
    out2[traj] = y;                         // row 0 = y0
    f32x2* __restrict__ op = out2 + traj;   // walking output pointer

    #pragma unroll 16
    for (int t = 0; t < NT - 1; ++t) {
        const f32x4 u = u4[t];
        const float h2 = u.x, h6 = u.y, D = u.z, dt = u.w;

        // once per step, off the stage chain
        const float sK  = K_m + s;          // K_m + s
        const float ses = s_e - s;          // s_e - s
        const float ms  = mu_max * s;

        // stage 1 (ss = s, bb = b)
        const float inv1 = __builtin_amdgcn_rcpf(sK);
        const float num1 = ms * b;
        const float rb1  = num1 * inv1;
        const float k1b  = __builtin_fmaf(-D, b, rb1);
        const float k1s  = __builtin_fmaf(D, ses, -rb1);

        // stage 2
        const float den2 = __builtin_fmaf(h2, k1s, sK);   // K_m + (s + h2*k1s)
        const float inv2 = __builtin_amdgcn_rcpf(den2);
        const float bb2  = __builtin_fmaf(h2, k1b, b);
        const float ss2  = __builtin_fmaf(h2, k1s, s);
        const float num2 = (mu_max * ss2) * bb2;
        const float rb2  = num2 * inv2;
        const float k2b  = __builtin_fmaf(-D, bb2, rb2);
        const float k2s  = __builtin_fmaf(D, s_e - ss2, -rb2);

        // stage 3
        const float den3 = __builtin_fmaf(h2, k2s, sK);
        const float inv3 = __builtin_amdgcn_rcpf(den3);
        const float bb3  = __builtin_fmaf(h2, k2b, b);
        const float ss3  = __builtin_fmaf(h2, k2s, s);
        const float num3 = (mu_max * ss3) * bb3;
        const float rb3  = num3 * inv3;
        const float k3b  = __builtin_fmaf(-D, bb3, rb3);
        const float k3s  = __builtin_fmaf(D, s_e - ss3, -rb3);

        // stage 4 (full dt)
        const float den4 = __builtin_fmaf(dt, k3s, sK);
        const float inv4 = __builtin_amdgcn_rcpf(den4);
        const float bb4  = __builtin_fmaf(dt, k3b, b);
        const float ss4  = __builtin_fmaf(dt, k3s, s);
        const float num4 = (mu_max * ss4) * bb4;
        const float rb4  = num4 * inv4;
        const float k4b  = __builtin_fmaf(-D, bb4, rb4);
        const float k4s  = __builtin_fmaf(D, s_e - ss4, -rb4);

        // parallel reduction trees + update
        const float sb  = (k1b + k4b) + 2.0f * (k2b + k3b);
        const float ss_ = (k1s + k4s) + 2.0f * (k2s + k3s);
        b = __builtin_fmaf(h6, sb, b);
        s = __builtin_fmaf(h6, ss_, s);

        op += NB;
        f32x2 v; v.x = b; v.y = s;
        *op = v;
    }
}

extern "C" void kernel_launch(void* const* d_in, const int* in_sizes, int n_in,
                              void* d_out, int out_size, void* d_ws, size_t ws_size,
                              hipStream_t stream) {
    const float* y0     = (const float*)d_in[0];
    const float* t_eval = (const float*)d_in[1];
    const float* D_seq  = (const float*)d_in[2];
    const float* K_m    = (const float*)d_in[3];
    const float* s_e    = (const float*)d_in[4];
    const float* mu_max = (const float*)d_in[5];
    float* out = (float*)d_out;

    dim3 grid(NB / 256);
    dim3 block(256);
    rk4_biosystem_kernel<<<grid, block, 0, stream>>>(y0, t_eval, D_seq, K_m, s_e, mu_max, out);
}

// Round 15
// 59.639 us; speedup vs baseline: 1.1088x; 1.0196x over previous
//
#include <hip/hip_runtime.h>

// Problem constants (match reference.py)
#define NB 65536   // trajectories
#define NT 512     // time points (NT-1 steps)

typedef float f32x2 __attribute__((ext_vector_type(2)));
typedef float f32x4 __attribute__((ext_vector_type(4)));

// R15 = R14 (60.8us best) with unroll 16 -> 32 (last untested knob).
// Structure: 1 traj/thread (1 wave/SIMD, fixed TLP budget); uniforms via one
// ds_read_b128/step from LDS (lgkm path); plain cached stores; full register
// budget (launch_bounds min-waves=1). Ledger: TLP trades -49..68%, vmcnt-path
// uniforms -48%, any footprint growth ~3.4 cyc/inst, issue trims null,
// unroll 8->16 -2.7%. Floor: max(chain ~40us, write-drain ~39us).
__global__ __launch_bounds__(256, 1) void rk4_biosystem_kernel(
    const float* __restrict__ y0,
    const float* __restrict__ t_eval,
    const float* __restrict__ D_seq,
    const float* __restrict__ K_m_p,
    const float* __restrict__ s_e_p,
    const float* __restrict__ mu_max_p,
    float* __restrict__ out)
{
    __shared__ f32x4 u4[NT];   // {h2, h6, D, dt} per step; 8 KiB

    const int tid = threadIdx.x;
    for (int i = tid; i < NT; i += 256) {
        const int j = (i < NT - 1) ? i : (NT - 2);   // pad tail (never used)
        const float dt = t_eval[j + 1] - t_eval[j];  // dt exactly as reference
        f32x4 v;
        v.x = dt * 0.5f;
        v.y = dt * (1.0f / 6.0f);
        v.z = D_seq[j];
        v.w = dt;
        u4[i] = v;
    }
    __syncthreads();

    const float K_m    = K_m_p[0];
    const float s_e    = s_e_p[0];
    const float mu_max = mu_max_p[0];

    const int traj = blockIdx.x * 256 + tid;

    const f32x2* __restrict__ y0v = (const f32x2*)y0;
    f32x2 y = y0v[traj];                    // (b, s)
    float b = y.x, s = y.y;

    f32x2* __restrict__ out2 = (f32x2*)out; // out[t][traj][2] as vec2
    out2[traj] = y;                         // row 0 = y0
    f32x2* __restrict__ op = out2 + traj;   // walking output pointer

    #pragma unroll 32
    for (int t = 0; t < NT - 1; ++t) {
        const f32x4 u = u4[t];
        const float h2 = u.x, h6 = u.y, D = u.z, dt = u.w;

        // once per step, off the stage chain
        const float sK  = K_m + s;          // K_m + s
        const float ses = s_e - s;          // s_e - s
        const float ms  = mu_max * s;

        // stage 1 (ss = s, bb = b)
        const float inv1 = __builtin_amdgcn_rcpf(sK);
        const float num1 = ms * b;
        const float rb1  = num1 * inv1;
        const float k1b  = __builtin_fmaf(-D, b, rb1);
        const float k1s  = __builtin_fmaf(D, ses, -rb1);

        // stage 2
        const float den2 = __builtin_fmaf(h2, k1s, sK);   // K_m + (s + h2*k1s)
        const float inv2 = __builtin_amdgcn_rcpf(den2);
        const float bb2  = __builtin_fmaf(h2, k1b, b);
        const float ss2  = __builtin_fmaf(h2, k1s, s);
        const float num2 = (mu_max * ss2) * bb2;
        const float rb2  = num2 * inv2;
        const float k2b  = __builtin_fmaf(-D, bb2, rb2);
        const float k2s  = __builtin_fmaf(D, s_e - ss2, -rb2);

        // stage 3
        const float den3 = __builtin_fmaf(h2, k2s, sK);
        const float inv3 = __builtin_amdgcn_rcpf(den3);
        const float bb3  = __builtin_fmaf(h2, k2b, b);
        const float ss3  = __builtin_fmaf(h2, k2s, s);
        const float num3 = (mu_max * ss3) * bb3;
        const float rb3  = num3 * inv3;
        const float k3b  = __builtin_fmaf(-D, bb3, rb3);
        const float k3s  = __builtin_fmaf(D, s_e - ss3, -rb3);

        // stage 4 (full dt)
        const float den4 = __builtin_fmaf(dt, k3s, sK);
        const float inv4 = __builtin_amdgcn_rcpf(den4);
        const float bb4  = __builtin_fmaf(dt, k3b, b);
        const float ss4  = __builtin_fmaf(dt, k3s, s);
        const float num4 = (mu_max * ss4) * bb4;
        const float rb4  = num4 * inv4;
        const float k4b  = __builtin_fmaf(-D, bb4, rb4);
        const float k4s  = __builtin_fmaf(D, s_e - ss4, -rb4);

        // parallel reduction trees + update
        const float sb  = (k1b + k4b) + 2.0f * (k2b + k3b);
        const float ss_ = (k1s + k4s) + 2.0f * (k2s + k3s);
        b = __builtin_fmaf(h6, sb, b);
        s = __builtin_fmaf(h6, ss_, s);

        op += NB;
        f32x2 v; v.x = b; v.y = s;
        *op = v;
    }
}

extern "C" void kernel_launch(void* const* d_in, const int* in_sizes, int n_in,
                              void* d_out, int out_size, void* d_ws, size_t ws_size,
                              hipStream_t stream) {
    const float* y0     = (const float*)d_in[0];
    const float* t_eval = (const float*)d_in[1];
    const float* D_seq  = (const float*)d_in[2];
    const float* K_m    = (const float*)d_in[3];
    const float* s_e    = (const float*)d_in[4];
    const float* mu_max = (const float*)d_in[5];
    float* out = (float*)d_out;

    dim3 grid(NB / 256);
    dim3 block(256);
    rk4_biosystem_kernel<<<grid, block, 0, stream>>>(y0, t_eval, D_seq, K_m, s_e, mu_max, out);
}

// Round 16
// 59.386 us; speedup vs baseline: 1.1135x; 1.0043x over previous
//
#include <hip/hip_runtime.h>

// Problem constants (match reference.py)
#define NB 65536   // trajectories
#define NT 512     // time points (NT-1 steps)

typedef float f32x2 __attribute__((ext_vector_type(2)));
typedef float f32x4 __attribute__((ext_vector_type(4)));

// R16 = R15 (59.6us best) with unroll 32 -> 64 (final notch; ~26KB body,
// still under 32KB L1I). Structure: 1 traj/thread (1 wave/SIMD, fixed TLP
// budget); uniforms via one ds_read_b128/step from LDS (lgkm path); plain
// cached stores; full register budget (launch_bounds min-waves=1).
// Ledger: TLP trades -49..68%, vmcnt-path uniforms -48%, footprint growth
// ~3.4 cyc/inst, issue trims null, unroll 8->16->32 = -2.7%, -2%.
// Floor: max(chain ~40us, write-drain ~39us).
__global__ __launch_bounds__(256, 1) void rk4_biosystem_kernel(
    const float* __restrict__ y0,
    const float* __restrict__ t_eval,
    const float* __restrict__ D_seq,
    const float* __restrict__ K_m_p,
    const float* __restrict__ s_e_p,
    const float* __restrict__ mu_max_p,
    float* __restrict__ out)
{
    __shared__ f32x4 u4[NT];   // {h2, h6, D, dt} per step; 8 KiB

    const int tid = threadIdx.x;
    for (int i = tid; i < NT; i += 256) {
        const int j = (i < NT - 1) ? i : (NT - 2);   // pad tail (never used)
        const float dt = t_eval[j + 1] - t_eval[j];  // dt exactly as reference
        f32x4 v;
        v.x = dt * 0.5f;
        v.y = dt * (1.0f / 6.0f);
        v.z = D_seq[j];
        v.w = dt;
        u4[i] = v;
    }
    __syncthreads();

    const float K_m    = K_m_p[0];
    const float s_e    = s_e_p[0];
    const float mu_max = mu_max_p[0];

    const int traj = blockIdx.x * 256 + tid;

    const f32x2* __restrict__ y0v = (const f32x2*)y0;
    f32x2 y = y0v[traj];                    // (b, s)
    float b = y.x, s = y.y;

    f32x2* __restrict__ out2 = (f32x2*)out; // out[t][traj][2] as vec2
    out2[traj] = y;                         // row 0 = y0
    f32x2* __restrict__ op = out2 + traj;   // walking output pointer

    #pragma unroll 64
    for (int t = 0; t < NT - 1; ++t) {
        const f32x4 u = u4[t];
        const float h2 = u.x, h6 = u.y, D = u.z, dt = u.w;

        // once per step, off the stage chain
        const float sK  = K_m + s;          // K_m + s
        const float ses = s_e - s;          // s_e - s
        const float ms  = mu_max * s;

        // stage 1 (ss = s, bb = b)
        const float inv1 = __builtin_amdgcn_rcpf(sK);
        const float num1 = ms * b;
        const float rb1  = num1 * inv1;
        const float k1b  = __builtin_fmaf(-D, b, rb1);
        const float k1s  = __builtin_fmaf(D, ses, -rb1);

        // stage 2
        const float den2 = __builtin_fmaf(h2, k1s, sK);   // K_m + (s + h2*k1s)
        const float inv2 = __builtin_amdgcn_rcpf(den2);
        const float bb2  = __builtin_fmaf(h2, k1b, b);
        const float ss2  = __builtin_fmaf(h2, k1s, s);
        const float num2 = (mu_max * ss2) * bb2;
        const float rb2  = num2 * inv2;
        const float k2b  = __builtin_fmaf(-D, bb2, rb2);
        const float k2s  = __builtin_fmaf(D, s_e - ss2, -rb2);

        // stage 3
        const float den3 = __builtin_fmaf(h2, k2s, sK);
        const float inv3 = __builtin_amdgcn_rcpf(den3);
        const float bb3  = __builtin_fmaf(h2, k2b, b);
        const float ss3  = __builtin_fmaf(h2, k2s, s);
        const float num3 = (mu_max * ss3) * bb3;
        const float rb3  = num3 * inv3;
        const float k3b  = __builtin_fmaf(-D, bb3, rb3);
        const float k3s  = __builtin_fmaf(D, s_e - ss3, -rb3);

        // stage 4 (full dt)
        const float den4 = __builtin_fmaf(dt, k3s, sK);
        const float inv4 = __builtin_amdgcn_rcpf(den4);
        const float bb4  = __builtin_fmaf(dt, k3b, b);
        const float ss4  = __builtin_fmaf(dt, k3s, s);
        const float num4 = (mu_max * ss4) * bb4;
        const float rb4  = num4 * inv4;
        const float k4b  = __builtin_fmaf(-D, bb4, rb4);
        const float k4s  = __builtin_fmaf(D, s_e - ss4, -rb4);

        // parallel reduction trees + update
        const float sb  = (k1b + k4b) + 2.0f * (k2b + k3b);
        const float ss_ = (k1s + k4s) + 2.0f * (k2s + k3s);
        b = __builtin_fmaf(h6, sb, b);
        s = __builtin_fmaf(h6, ss_, s);

        op += NB;
        f32x2 v; v.x = b; v.y = s;
        *op = v;
    }
}

extern "C" void kernel_launch(void* const* d_in, const int* in_sizes, int n_in,
                              void* d_out, int out_size, void* d_ws, size_t ws_size,
                              hipStream_t stream) {
    const float* y0     = (const float*)d_in[0];
    const float* t_eval = (const float*)d_in[1];
    const float* D_seq  = (const float*)d_in[2];
    const float* K_m    = (const float*)d_in[3];
    const float* s_e    = (const float*)d_in[4];
    const float* mu_max = (const float*)d_in[5];
    float* out = (float*)d_out;

    dim3 grid(NB / 256);
    dim3 block(256);
    rk4_biosystem_kernel<<<grid, block, 0, stream>>>(y0, t_eval, D_seq, K_m, s_e, mu_max, out);
}